// Round 5
// baseline (405.525 us; speedup 1.0000x reference)
//
#include <hip/hip_runtime.h>

#define NE 500000      // edges
#define DIMK 256       // embedding dim
#define H1 128
#define H2 64
#define EPSBN 1e-5f
#define NT1 977                  // layer1 tiles of 512 edges
#define GRID2 1024
#define NJOBS2 1954              // layer2 tiles of 256 edges

typedef _Float16 half8 __attribute__((ext_vector_type(8)));
typedef float f32x4 __attribute__((ext_vector_type(4)));
typedef unsigned short ushort8 __attribute__((ext_vector_type(8)));

static __device__ __forceinline__ half8 habs8(half8 x) {
  ushort8 u = __builtin_bit_cast(ushort8, x);
  u &= (unsigned short)0x7FFF;
  return __builtin_bit_cast(half8, u);
}
static __device__ __forceinline__ float h2f(unsigned int u) {
  return (float)__builtin_bit_cast(_Float16, (unsigned short)(u & 0xffff));
}

// c0[j] = b1[j] + step @ W1[768:800, j]
__global__ void k_prep(const float* __restrict__ W1, const float* __restrict__ b1,
                       const float* __restrict__ step, float* __restrict__ c0) {
  const int j = threadIdx.x;
  if (j < H1) {
    float a = b1[j];
#pragma unroll
    for (int tt = 0; tt < 32; ++tt) a += step[tt] * W1[(768 + tt) * H1 + j];
    c0[j] = a;
  }
}

// fp32 emb -> fp16 copy (12.8M elems, 8/thread, exact grid)
__global__ void k_prep16(const float* __restrict__ emb, _Float16* __restrict__ embh) {
  const int i = (blockIdx.x * 256 + threadIdx.x) * 8;
  const float4 a = *(const float4*)(emb + i);
  const float4 b = *(const float4*)(emb + i + 4);
  half8 h;
  h[0] = (_Float16)a.x; h[1] = (_Float16)a.y; h[2] = (_Float16)a.z; h[3] = (_Float16)a.w;
  h[4] = (_Float16)b.x; h[5] = (_Float16)b.y; h[6] = (_Float16)b.z; h[7] = (_Float16)b.w;
  *(half8*)(embh + i) = h;
}

// Fragment-ordered B for layer1: bfrag[(s*64+kc*8+c)*64*8 + lane*8 + j]
//   = W1[s*256 + kc*32 + (lane>>4)*8 + j][c*16 + (lane&15)]   (fp16)
__global__ void k_prepB(const float* __restrict__ W1, _Float16* __restrict__ bfrag) {
  const int g = blockIdx.x * 256 + threadIdx.x;
  const int lane = g & 63, f = g >> 6;
  const int c = f & 7, kc = (f >> 3) & 7, s = f >> 6;
  const int row0 = s * 256 + kc * 32 + (lane >> 4) * 8;
  const int col = c * 16 + (lane & 15);
  half8 h;
#pragma unroll
  for (int j = 0; j < 8; ++j) h[j] = (_Float16)W1[(row0 + j) * H1 + col];
  *(half8*)(bfrag + (size_t)g * 8) = h;
}

// Layer 1 via MFMA fp16. 256 blocks x 1024 threads; block covers a 64-col
// half (LDS-resident B, loaded once, no barriers in K-loop) and tiles of
// 512 edges. Wave = 32 rows x 64 cols -> acc 32 AGPR, <=128 regs/wave ->
// 16 waves/CU for gather-latency hiding.
__global__ __launch_bounds__(1024, 4)
void k_layer1(const _Float16* __restrict__ embh, const void* __restrict__ eidx_raw,
              const float* __restrict__ grad, const float* __restrict__ W1,
              const float* __restrict__ c0, const _Float16* __restrict__ bfrag,
              _Float16* __restrict__ x1, float* __restrict__ p1) {
  __shared__ __align__(16) _Float16 ldsB[49152];   // 98,304 B: 768K x 64 cols, frag order
  __shared__ int s_src[512], s_dst[512];
  __shared__ float s_g[512];
  __shared__ float s_wg[64], s_c0[64], s_sum[64], s_sq[64];

  const int t = threadIdx.x, bid = blockIdx.x;
  const int ch = bid & 1;                 // col half: cols [ch*64, ch*64+64)
  const int w = t >> 6, lane = t & 63, quad = lane >> 4, m15 = lane & 15;

  // stage B half into LDS once: 6144 half8 units, fl = (s*8+kc)*4 + c
  {
    const half8* gb = (const half8*)bfrag;
    half8* lb = (half8*)ldsB;
    for (int i = t; i < 6144; i += 1024) {
      const int li = i & 63, fl = i >> 6;
      const int c = fl & 3, kc = (fl >> 2) & 7, s = fl >> 5;
      lb[i] = gb[(size_t)((s * 64 + kc * 8 + ch * 4 + c) * 64 + li)];
    }
  }
  if (t < 64) {
    s_wg[t] = W1[800 * H1 + ch * 64 + t];
    s_c0[t] = c0[ch * 64 + t];
    s_sum[t] = 0.f; s_sq[t] = 0.f;
  }

  const unsigned* ew = (const unsigned*)eidx_raw;
  const bool is64 = ((ew[1] | ew[3] | ew[5] | ew[7]) == 0u);
  const int* e32 = (const int*)eidx_raw;
  const long long* e64 = (const long long*)eidx_raw;

  float st_s[4] = {0, 0, 0, 0}, st_q[4] = {0, 0, 0, 0};
  const half8* lb = (const half8*)ldsB;

  for (int tile = (bid >> 1); tile < NT1; tile += 128) {
    const int base = tile * 512;
    __syncthreads();                      // protect s_src/s_g reuse
    if (t < 512) {
      int e = base + t; if (e >= NE) e = NE - 1;
      if (is64) { s_src[t] = (int)e64[e]; s_dst[t] = (int)e64[NE + e]; }
      else      { s_src[t] = e32[e];      s_dst[t] = e32[NE + e]; }
      s_g[t] = grad[e];
    }
    __syncthreads();                      // also orders initial B staging

    const int row0 = w * 32 + m15;
    const _Float16* pu0 = embh + (size_t)s_src[row0] * DIMK + quad * 8;
    const _Float16* pv0 = embh + (size_t)s_dst[row0] * DIMK + quad * 8;
    const _Float16* pu1 = embh + (size_t)s_src[row0 + 16] * DIMK + quad * 8;
    const _Float16* pv1 = embh + (size_t)s_dst[row0 + 16] * DIMK + quad * 8;

    f32x4 acc[2][4];
#pragma unroll
    for (int r = 0; r < 2; ++r)
#pragma unroll
      for (int c = 0; c < 4; ++c) acc[r][c] = (f32x4)0.f;

#pragma unroll 1
    for (int kc = 0; kc < 8; ++kc) {
      const half8 u0 = *(const half8*)(pu0 + kc * 32);
      const half8 v0 = *(const half8*)(pv0 + kc * 32);
      const half8 u1 = *(const half8*)(pu1 + kc * 32);
      const half8 v1 = *(const half8*)(pv1 + kc * 32);
      const half8 d0 = habs8(u0 - v0);
      const half8 d1 = habs8(u1 - v1);
#pragma unroll
      for (int c = 0; c < 4; ++c) {
        const half8 bu = lb[((0 * 8 + kc) * 4 + c) * 64 + lane];
        const half8 bv = lb[((1 * 8 + kc) * 4 + c) * 64 + lane];
        const half8 bd = lb[((2 * 8 + kc) * 4 + c) * 64 + lane];
        acc[0][c] = __builtin_amdgcn_mfma_f32_16x16x32_f16(u0, bu, acc[0][c], 0, 0, 0);
        acc[1][c] = __builtin_amdgcn_mfma_f32_16x16x32_f16(u1, bu, acc[1][c], 0, 0, 0);
        acc[0][c] = __builtin_amdgcn_mfma_f32_16x16x32_f16(v0, bv, acc[0][c], 0, 0, 0);
        acc[1][c] = __builtin_amdgcn_mfma_f32_16x16x32_f16(v1, bv, acc[1][c], 0, 0, 0);
        acc[0][c] = __builtin_amdgcn_mfma_f32_16x16x32_f16(d0, bd, acc[0][c], 0, 0, 0);
        acc[1][c] = __builtin_amdgcn_mfma_f32_16x16x32_f16(d1, bd, acc[1][c], 0, 0, 0);
      }
    }
    // epilogue: D layout col=lane&15, row=quad*4+reg
#pragma unroll
    for (int r = 0; r < 2; ++r) {
      const int rrow = w * 32 + r * 16 + quad * 4;
#pragma unroll
      for (int c = 0; c < 4; ++c) {
        const int colL = c * 16 + m15;
        const float wgv = s_wg[colL], c0v = s_c0[colL];
#pragma unroll
        for (int reg = 0; reg < 4; ++reg) {
          const int e = base + rrow + reg;
          float x = acc[r][c][reg] + s_g[rrow + reg] * wgv + c0v;
          x = fmaxf(x, 0.f);
          if (e >= NE) x = 0.f;
          st_s[c] += x; st_q[c] += x * x;
          if (e < NE) x1[(size_t)e * H1 + ch * 64 + colL] = (_Float16)x;
        }
      }
    }
  }
  __syncthreads();
#pragma unroll
  for (int c = 0; c < 4; ++c) {
    float a = st_s[c]; a += __shfl_xor(a, 16); a += __shfl_xor(a, 32);
    float b = st_q[c]; b += __shfl_xor(b, 16); b += __shfl_xor(b, 32);
    if (lane < 16) { atomicAdd(&s_sum[c * 16 + m15], a); atomicAdd(&s_sq[c * 16 + m15], b); }
  }
  __syncthreads();
  if (t < 64) {
    const int colG = ch * 64 + t, bh = bid >> 1;
    p1[colG * 128 + bh] = s_sum[t];
    p1[128 * 128 + colG * 128 + bh] = s_sq[t];
  }
}

// Finalize BN1 stats (partial width 128), fold into W2/b2
__global__ void k_fin1(const float* __restrict__ p1, const float* __restrict__ g1,
                       const float* __restrict__ be1, const float* __restrict__ W2,
                       const float* __restrict__ b2, float* __restrict__ w2f,
                       float* __restrict__ b2f) {
  __shared__ float s1[128], t1[128];
  const int t = threadIdx.x;
  if (t < 128) {
    float s = 0.f, q = 0.f;
    const float4* rs = (const float4*)(p1 + t * 128);
    const float4* rq = (const float4*)(p1 + 128 * 128 + t * 128);
#pragma unroll 4
    for (int i = 0; i < 32; ++i) {
      float4 a = rs[i]; s += a.x + a.y + a.z + a.w;
      float4 b = rq[i]; q += b.x + b.y + b.z + b.w;
    }
    const float inv = 1.0f / (float)NE;
    float mean = s * inv;
    float var = q * inv - mean * mean;
    float sc = g1[t] * rsqrtf(var + EPSBN);
    s1[t] = sc; t1[t] = be1[t] - mean * sc;
  }
  __syncthreads();
  for (int i = t; i < H1 * H2; i += 256) w2f[i] = s1[i >> 6] * W2[i];
  if (t < 64) {
    float b = b2[t];
    for (int j = 0; j < 128; ++j) b += t1[j] * W2[j * 64 + t];
    b2f[t] = b;
  }
}

// Layer 2 via MFMA: x2 = relu(x1 @ W2F + b2F), B (16KB) resident in LDS
__global__ __launch_bounds__(256, 2)
void k_layer2(const _Float16* __restrict__ x1, const float* __restrict__ w2f,
              const float* __restrict__ b2f, _Float16* __restrict__ x2,
              float* __restrict__ p2) {
  __shared__ __align__(16) _Float16 b_lds[8192];  // 4 ksteps x 4 coltiles frag order
  __shared__ float s_b[64], s_sum[64], s_sq[64];
  const int t = threadIdx.x, bid = blockIdx.x;
  const int w = t >> 6, lane = t & 63, quad = lane >> 4, m15 = lane & 15;

  for (int i = t; i < 8192; i += 256) {
    const int j = i & 7, li = (i >> 3) & 63, f = i >> 9;
    const int c = f & 3, kk = f >> 2;
    const int row = kk * 32 + (li >> 4) * 8 + j;
    const int col = c * 16 + (li & 15);
    b_lds[i] = (_Float16)w2f[row * H2 + col];
  }
  if (t < 64) { s_b[t] = b2f[t]; s_sum[t] = 0.f; s_sq[t] = 0.f; }
  __syncthreads();

  float st_s[4] = {0, 0, 0, 0}, st_q[4] = {0, 0, 0, 0};
  const half8* bp = (const half8*)b_lds;

  for (int job = bid; job < NJOBS2; job += GRID2) {
    const int base = job * 256;
    const _Float16* pa[4];
#pragma unroll
    for (int r = 0; r < 4; ++r) {
      int e = base + w * 64 + r * 16 + m15; if (e >= NE) e = NE - 1;
      pa[r] = x1 + (size_t)e * H1 + quad * 8;
    }
    f32x4 acc[4][4];
#pragma unroll
    for (int r = 0; r < 4; ++r)
#pragma unroll
      for (int c = 0; c < 4; ++c) acc[r][c] = (f32x4)0.f;

#pragma unroll
    for (int kk = 0; kk < 4; ++kk) {
      half8 a[4];
#pragma unroll
      for (int r = 0; r < 4; ++r) a[r] = *(const half8*)(pa[r] + kk * 32);
#pragma unroll
      for (int c = 0; c < 4; ++c) {
        const half8 bf = bp[(kk * 4 + c) * 64 + lane];
#pragma unroll
        for (int r = 0; r < 4; ++r)
          acc[r][c] = __builtin_amdgcn_mfma_f32_16x16x32_f16(a[r], bf, acc[r][c], 0, 0, 0);
      }
    }
#pragma unroll
    for (int r = 0; r < 4; ++r) {
      const int erow = w * 64 + r * 16 + quad * 4;
#pragma unroll
      for (int c = 0; c < 4; ++c) {
        const int colL = c * 16 + m15;
        const float bv = s_b[colL];
#pragma unroll
        for (int reg = 0; reg < 4; ++reg) {
          const int e = base + erow + reg;
          float x = acc[r][c][reg] + bv;
          x = fmaxf(x, 0.f);
          if (e >= NE) x = 0.f;
          st_s[c] += x; st_q[c] += x * x;
          if (e < NE) x2[(size_t)e * H2 + colL] = (_Float16)x;
        }
      }
    }
  }
  __syncthreads();
#pragma unroll
  for (int c = 0; c < 4; ++c) {
    float a = st_s[c]; a += __shfl_xor(a, 16); a += __shfl_xor(a, 32);
    float b = st_q[c]; b += __shfl_xor(b, 16); b += __shfl_xor(b, 32);
    if (lane < 16) { atomicAdd(&s_sum[c * 16 + m15], a); atomicAdd(&s_sq[c * 16 + m15], b); }
  }
  __syncthreads();
  if (t < 64) {
    p2[t * GRID2 + bid] = s_sum[t];
    p2[64 * GRID2 + t * GRID2 + bid] = s_sq[t];
  }
}

// Finalize BN2, fold into W3/b3
__global__ void k_fin2(const float* __restrict__ p2, const float* __restrict__ g2,
                       const float* __restrict__ be2, const float* __restrict__ W3,
                       const float* __restrict__ b3, float* __restrict__ w3f,
                       float* __restrict__ b3f) {
  __shared__ float tp[64];
  const int t = threadIdx.x;
  if (t < 64) {
    float s = 0.f, q = 0.f;
    const float4* rs = (const float4*)(p2 + t * GRID2);
    const float4* rq = (const float4*)(p2 + 64 * GRID2 + t * GRID2);
#pragma unroll 4
    for (int i = 0; i < GRID2 / 4; ++i) {
      float4 a = rs[i]; s += a.x + a.y + a.z + a.w;
      float4 b = rq[i]; q += b.x + b.y + b.z + b.w;
    }
    const float inv = 1.0f / (float)NE;
    float mean = s * inv;
    float var = q * inv - mean * mean;
    float sc = g2[t] * rsqrtf(var + EPSBN);
    float tt = be2[t] - mean * sc;
    w3f[t] = sc * W3[t];
    tp[t] = tt * W3[t];
  }
  __syncthreads();
  if (t == 0) {
    float b = b3[0];
    for (int j = 0; j < 64; ++j) b += tp[j];
    b3f[0] = b;
  }
}

// out = tanh(x2 @ w3f + b3f); 4 lanes per edge
__global__ __launch_bounds__(256)
void k_out(const unsigned short* __restrict__ x2, const float* __restrict__ w3f,
           const float* __restrict__ b3f, float* __restrict__ out) {
  __shared__ float s_w[64];
  __shared__ float s_b;
  const int t = threadIdx.x;
  if (t < 64) s_w[t] = w3f[t];
  if (t == 0) s_b = b3f[0];
  __syncthreads();
  const int gid = blockIdx.x * 256 + t;
  const int e = gid >> 2, p = gid & 3;
  if (e < NE) {
    const uint4* r = (const uint4*)(x2 + (size_t)e * H2 + p * 16);
    float s = 0.f;
#pragma unroll
    for (int i = 0; i < 2; ++i) {
      const uint4 u = r[i];
      const int jb = p * 16 + i * 8;
      s += h2f(u.x) * s_w[jb + 0] + h2f(u.x >> 16) * s_w[jb + 1];
      s += h2f(u.y) * s_w[jb + 2] + h2f(u.y >> 16) * s_w[jb + 3];
      s += h2f(u.z) * s_w[jb + 4] + h2f(u.z >> 16) * s_w[jb + 5];
      s += h2f(u.w) * s_w[jb + 6] + h2f(u.w >> 16) * s_w[jb + 7];
    }
    s += __shfl_xor(s, 1);
    s += __shfl_xor(s, 2);
    if (p == 0) out[e] = tanhf(s + s_b);
  }
}

extern "C" void kernel_launch(void* const* d_in, const int* in_sizes, int n_in,
                              void* d_out, int out_size, void* d_ws, size_t ws_size,
                              hipStream_t stream) {
  const float* emb  = (const float*)d_in[0];
  const float* grad = (const float*)d_in[1];
  const float* step = (const float*)d_in[2];
  const float* W1   = (const float*)d_in[3];
  const float* b1   = (const float*)d_in[4];
  const float* g1   = (const float*)d_in[5];
  const float* be1  = (const float*)d_in[6];
  const float* W2   = (const float*)d_in[7];
  const float* b2   = (const float*)d_in[8];
  const float* g2   = (const float*)d_in[9];
  const float* be2  = (const float*)d_in[10];
  const float* W3   = (const float*)d_in[11];
  const float* b3   = (const float*)d_in[12];
  const void*  eidx = (const void*)d_in[13];
  float* out = (float*)d_out;

  char* ws = (char*)d_ws;
  // region A (64MB): embh + bfrag + c0 during layer1; x2 overwrites in layer2
  _Float16* embh  = (_Float16*)(ws + 0);
  _Float16* x2    = (_Float16*)(ws + 0);
  _Float16* bfrag = (_Float16*)(ws + 25600000LL);  // 196,608 B
  float*    c0    = (float*)(ws + 25796608LL);     // 512 B
  _Float16* x1    = (_Float16*)(ws + 64000000LL);  // 128,000,000 B
  float* p1  = (float*)(ws + 192000000LL);         // 131,072 B (128 x 128 x 2)
  float* p2  = (float*)(ws + 192131072LL);         // 524,288 B (64 x 1024 x 2)
  float* w2f = (float*)(ws + 192655360LL);         // 32,768 B
  float* b2f = (float*)(ws + 192688128LL);         // 256 B
  float* w3f = (float*)(ws + 192688384LL);         // 256 B
  float* b3f = (float*)(ws + 192688640LL);         // 16 B

  k_prep  <<<1,    256, 0, stream>>>(W1, b1, step, c0);
  k_prep16<<<6250, 256, 0, stream>>>(emb, embh);
  k_prepB <<<48,   256, 0, stream>>>(W1, bfrag);
  k_layer1<<<256, 1024, 0, stream>>>(embh, eidx, grad, W1, c0, bfrag, x1, p1);
  k_fin1  <<<1,    256, 0, stream>>>(p1, g1, be1, W2, b2, w2f, b2f);
  k_layer2<<<GRID2,256, 0, stream>>>(x1, w2f, b2f, x2, p2);
  k_fin2  <<<1,    128, 0, stream>>>(p2, g2, be2, W3, b3, w3f, b3f);
  k_out   <<<7813, 256, 0, stream>>>((const unsigned short*)x2, w3f, b3f, out);
}